// Round 17
// baseline (973.693 us; speedup 1.0000x reference)
//
#include <hip/hip_runtime.h>
#include <hip/hip_bf16.h>

// GINBase: N=50000 nodes, E=512000 edges, D=64, L=4 layers.
// v14 = v13 + occupancy: edge_update eold in f32x4 regs (LDS 36.9->28.6KB,
// 5 blocks/CU; u16 reg-arrays spill but f32x4 static-indexed promote — proven
// by acc/s1v in this kernel), node_mlp LDS 55.8->51.7KB (3 blocks/CU).

#define GIN_N 50000
#define GIN_E 512000

typedef __attribute__((ext_vector_type(8))) short short8;
typedef __attribute__((ext_vector_type(4))) float f32x4;
typedef unsigned short u16;

__device__ __forceinline__ u16 bf16r(float x) {
    unsigned u = __builtin_bit_cast(unsigned, x);
    u += 0x7fffu + ((u >> 16) & 1u);
    return (u16)(u >> 16);
}
__device__ __forceinline__ float bf16f(u16 h) {
    unsigned u = ((unsigned)h) << 16;
    return __builtin_bit_cast(float, u);
}

// atom encode + agg zeroing fused (same N*64 domain)
__global__ __launch_bounds__(256) void atom_encode(const int* __restrict__ x,
        const float* __restrict__ emb, float* __restrict__ node,
        float* __restrict__ agg, int N) {
    int idx = blockIdx.x * 256 + threadIdx.x;
    int n = idx >> 6, lane = idx & 63;
    if (n >= N) return;
    float s = 0.f;
#pragma unroll
    for (int f = 0; f < 9; ++f) {
        int v = x[n * 9 + f];
        s += emb[(f * 119 + v) * 64 + lane];
    }
    size_t o = (size_t)n * 64 + lane;
    node[o] = s;
    agg[o] = 0.f;
}

// bond encode (bf16 out) + layer-0 message scatter fused (natural order)
__global__ __launch_bounds__(256) void bond_encode_scatter(
        const int* __restrict__ ea, const float* __restrict__ emb,
        u16* __restrict__ edgeB, const int* __restrict__ src,
        const int* __restrict__ dst, const float* __restrict__ node,
        float* __restrict__ agg, int E) {
    int idx = blockIdx.x * 256 + threadIdx.x;
    int e = idx >> 6, lane = idx & 63;
    if (e >= E) return;
    float s = 0.f;
#pragma unroll
    for (int f = 0; f < 3; ++f) {
        int v = ea[e * 3 + f];
        s += emb[(f * 6 + v) * 64 + lane];
    }
    edgeB[(size_t)e * 64 + lane] = bf16r(s);
    int si = src[e], di = dst[e];
    float msg = fmaxf(node[(size_t)si * 64 + lane] + s, 0.f);
    unsafeAtomicAdd(&agg[(size_t)di * 64 + lane], msg);
}

// ---------------- weight pre-pack into MFMA B-fragment order ----------------
__global__ __launch_bounds__(256) void pack_b1(const float* __restrict__ W,
        u16* __restrict__ out, int K, int Nc, int F) {
    int tid = blockIdx.x * 256 + threadIdx.x;
    int lane = tid & 63;
    int frag = (tid >> 6) % F;
    int layer = tid / (F * 64);
    int tpr = Nc / 16;
    int ks = frag / tpr, tt = frag % tpr;
    int k0 = ks * 32 + ((lane >> 4) << 3);
    int col = tt * 16 + (lane & 15);
    const float* w = W + (size_t)layer * K * Nc;
    u16* o = out + ((size_t)layer * F + frag) * 512 + (size_t)lane * 8;
#pragma unroll
    for (int j = 0; j < 8; ++j) o[j] = bf16r(w[(size_t)(k0 + j) * Nc + col]);
}
__global__ __launch_bounds__(256) void pack_b2(const float* __restrict__ W,
        u16* __restrict__ out, int K, int Nc, int F) {
    int tid = blockIdx.x * 256 + threadIdx.x;
    int lane = tid & 63;
    int frag = (tid >> 6) % F;
    int layer = tid / (F * 64);
    int tpr = Nc / 16;
    int ks = frag / tpr, tt = frag % tpr;
    int k0 = ks * 32 + ((lane >> 4) << 3);
    int col = tt * 16 + (lane & 15);
    const float* w = W + (size_t)layer * K * Nc;
    u16* o = out + ((size_t)layer * F + frag) * 1024 + (size_t)lane * 8;
#pragma unroll
    for (int j = 0; j < 8; ++j) {
        float v = w[(size_t)(k0 + j) * Nc + col];
        u16 hi = bf16r(v);
        o[j] = hi;
        o[512 + j] = bf16r(v - bf16f(hi));
    }
}

// ------------- node MLP (in-place): x=(1+eps)*node+agg; MFMA; LN; residual --
__global__ __launch_bounds__(256, 2) void node_mlp(
        float* __restrict__ node, u16* __restrict__ nodeB,
        float* __restrict__ agg,
        const float* __restrict__ epsArr, int l,
        const u16* __restrict__ pw1, const u16* __restrict__ pw2,
        const float* __restrict__ b1, const float* __restrict__ b2,
        const float* __restrict__ lng, const float* __restrict__ lnb, int N) {
    __shared__ u16 xH[64][68], xL[64][68];     // 51.7KB total -> 3 blocks/CU
    __shared__ u16 hH[64][132], hL[64][132];
    __shared__ float pS[4][64], pS2[4][64], lnM[64], lnR[64];
    const int t = threadIdx.x, w = t >> 6, lane = t & 63;
    const int g = lane >> 4, c0 = lane & 15;
    const float epf = 1.f + epsArr[l];

#pragma unroll
    for (int i = 0; i < 16; ++i) {
        int r = w * 16 + i;
        int n = blockIdx.x * 64 + r;
        float x = 0.f;
        if (n < N) {
            size_t o = (size_t)n * 64 + lane;
            x = epf * node[o] + agg[o];
            agg[o] = 0.f;
        }
        u16 h = bf16r(x);
        xH[r][lane] = h;
        xL[r][lane] = bf16r(x - bf16f(h));
    }
    __syncthreads();

    f32x4 a1[4][2];
#pragma unroll
    for (int sp = 0; sp < 4; ++sp)
#pragma unroll
        for (int lt = 0; lt < 2; ++lt) a1[sp][lt] = (f32x4)0.f;
#pragma unroll
    for (int ks = 0; ks < 2; ++ks) {
        short8 aH[4], aL[4];
#pragma unroll
        for (int sp = 0; sp < 4; ++sp) {
            aH[sp] = *(const short8*)&xH[sp * 16 + c0][ks * 32 + g * 8];
            aL[sp] = *(const short8*)&xL[sp * 16 + c0][ks * 32 + g * 8];
        }
#pragma unroll
        for (int lt = 0; lt < 2; ++lt) {
            const u16* p = pw1 + (size_t)(ks * 8 + w * 2 + lt) * 1024 + (size_t)lane * 8;
            short8 bH = *(const short8*)p;
            short8 bL = *(const short8*)(p + 512);
#pragma unroll
            for (int sp = 0; sp < 4; ++sp) {
                a1[sp][lt] = __builtin_amdgcn_mfma_f32_16x16x32_bf16(aH[sp], bH, a1[sp][lt], 0, 0, 0);
                a1[sp][lt] = __builtin_amdgcn_mfma_f32_16x16x32_bf16(aH[sp], bL, a1[sp][lt], 0, 0, 0);
                a1[sp][lt] = __builtin_amdgcn_mfma_f32_16x16x32_bf16(aL[sp], bH, a1[sp][lt], 0, 0, 0);
            }
        }
    }
#pragma unroll
    for (int lt = 0; lt < 2; ++lt) {
        int col = w * 32 + lt * 16 + c0;
        float bias = b1[col];
#pragma unroll
        for (int sp = 0; sp < 4; ++sp)
#pragma unroll
            for (int rg = 0; rg < 4; ++rg) {
                int r = sp * 16 + g * 4 + rg;
                float v = fmaxf(a1[sp][lt][rg] + bias, 0.f);
                u16 h = bf16r(v);
                hH[r][col] = h;
                hL[r][col] = bf16r(v - bf16f(h));
            }
    }
    __syncthreads();

    f32x4 a2[4];
#pragma unroll
    for (int sp = 0; sp < 4; ++sp) a2[sp] = (f32x4)0.f;
#pragma unroll
    for (int ks = 0; ks < 4; ++ks) {
        const u16* p = pw2 + (size_t)(ks * 4 + w) * 1024 + (size_t)lane * 8;
        short8 bH = *(const short8*)p;
        short8 bL = *(const short8*)(p + 512);
#pragma unroll
        for (int sp = 0; sp < 4; ++sp) {
            short8 aH = *(const short8*)&hH[sp * 16 + c0][ks * 32 + g * 8];
            short8 aL = *(const short8*)&hL[sp * 16 + c0][ks * 32 + g * 8];
            a2[sp] = __builtin_amdgcn_mfma_f32_16x16x32_bf16(aH, bH, a2[sp], 0, 0, 0);
            a2[sp] = __builtin_amdgcn_mfma_f32_16x16x32_bf16(aH, bL, a2[sp], 0, 0, 0);
            a2[sp] = __builtin_amdgcn_mfma_f32_16x16x32_bf16(aL, bH, a2[sp], 0, 0, 0);
        }
    }
    float bias2 = b2[w * 16 + c0];
    float s1v[4][4], s2v[4][4];
#pragma unroll
    for (int sp = 0; sp < 4; ++sp)
#pragma unroll
        for (int rg = 0; rg < 4; ++rg) {
            float v = a2[sp][rg] + bias2;
            a2[sp][rg] = v;
            s1v[sp][rg] = v;
            s2v[sp][rg] = v * v;
        }
#pragma unroll
    for (int off = 1; off < 16; off <<= 1)
#pragma unroll
        for (int sp = 0; sp < 4; ++sp)
#pragma unroll
            for (int rg = 0; rg < 4; ++rg) {
                s1v[sp][rg] += __shfl_xor(s1v[sp][rg], off);
                s2v[sp][rg] += __shfl_xor(s2v[sp][rg], off);
            }
    if (c0 == 0) {
#pragma unroll
        for (int sp = 0; sp < 4; ++sp)
#pragma unroll
            for (int rg = 0; rg < 4; ++rg) {
                int r = sp * 16 + g * 4 + rg;
                pS[w][r] = s1v[sp][rg];
                pS2[w][r] = s2v[sp][rg];
            }
    }
    __syncthreads();
    if (t < 64) {
        float a = pS[0][t] + pS[1][t] + pS[2][t] + pS[3][t];
        float b = pS2[0][t] + pS2[1][t] + pS2[2][t] + pS2[3][t];
        float mean = a * (1.f / 64.f);
        float var = b * (1.f / 64.f) - mean * mean;
        lnM[t] = mean;
        lnR[t] = rsqrtf(var + 1e-5f);
    }
    __syncthreads();

    int col = w * 16 + c0;
    float gg = lng[col], bc = lnb[col];
#pragma unroll
    for (int sp = 0; sp < 4; ++sp)
#pragma unroll
        for (int rg = 0; rg < 4; ++rg) {
            int r = sp * 16 + g * 4 + rg;
            int n = blockIdx.x * 64 + r;
            if (n < N) {
                size_t o = (size_t)n * 64 + col;
                float y = (a2[sp][rg] - lnM[r]) * lnR[r] * gg + bc;
                float out = fmaxf(y, 0.f) + node[o];
                node[o] = out;
                nodeB[o] = bf16r(out);
            }
        }
}

// ---- edge update v14: eold in f32x4 regs, LDS 28.6KB -> 5 blocks/CU --------
template <bool SCATTER>
__global__ __launch_bounds__(256, 4) void edge_update_v14(
        const int* __restrict__ src, const int* __restrict__ dst,
        const float* __restrict__ node, const u16* __restrict__ nodeB,
        u16* __restrict__ edgeB, float* __restrict__ edgeF,
        float* __restrict__ agg,
        const u16* __restrict__ pb1, const u16* __restrict__ pb2,
        const float* __restrict__ bu1, const float* __restrict__ ug,
        const float* __restrict__ ub, const float* __restrict__ bu2) {
    __shared__ u16 cat[64][200];    // 100 dwords/row: 2-way max on b128 A-frags
    __shared__ float pS[4][64], pS2[4][64];
    __shared__ float lnM[64], lnR[64];
    const int t = threadIdx.x, w = t >> 6, lane = t & 63;
    const int g = lane >> 4, c0 = lane & 15;
    const long eB = (long)blockIdx.x * 64;   // natural order

    // stage: pure u16 copies (v6/v13 pattern)
#pragma unroll
    for (int i = 0; i < 16; ++i) {
        int r = w * 16 + i;
        long ge = eB + r;
        int s = src[ge], d = dst[ge];
        cat[r][lane]       = nodeB[(size_t)s * 64 + lane];
        cat[r][64 + lane]  = nodeB[(size_t)d * 64 + lane];
        cat[r][128 + lane] = edgeB[(size_t)ge * 64 + lane];
    }
    __syncthreads();

    // edge_old -> f32x4 registers (static-indexed vector array: promotes;
    // the u16[16] scalar array variant spilled to scratch in v10/v12)
    f32x4 eoldf[4];
#pragma unroll
    for (int sp = 0; sp < 4; ++sp)
#pragma unroll
        for (int rg = 0; rg < 4; ++rg)
            eoldf[sp][rg] = bf16f(cat[sp * 16 + g * 4 + rg][128 + w * 16 + c0]);

    // GEMM1: m_pre = cat @ Wu1; wave w -> cols w*48..+47 (sp-reuse x4)
    f32x4 acc[4][3];
#pragma unroll
    for (int sp = 0; sp < 4; ++sp)
#pragma unroll
        for (int lt = 0; lt < 3; ++lt) acc[sp][lt] = (f32x4)0.f;
#pragma unroll
    for (int ks = 0; ks < 6; ++ks) {
        short8 a[4];
#pragma unroll
        for (int sp = 0; sp < 4; ++sp)
            a[sp] = *(const short8*)&cat[sp * 16 + c0][ks * 32 + g * 8];
#pragma unroll
        for (int lt = 0; lt < 3; ++lt) {
            const u16* p = pb1 + (size_t)(ks * 12 + w * 3 + lt) * 512 + (size_t)lane * 8;
            short8 b = *(const short8*)p;
#pragma unroll
            for (int sp = 0; sp < 4; ++sp)
                acc[sp][lt] = __builtin_amdgcn_mfma_f32_16x16x32_bf16(a[sp], b, acc[sp][lt], 0, 0, 0);
        }
    }

    float bs[3];
#pragma unroll
    for (int lt = 0; lt < 3; ++lt) bs[lt] = bu1[w * 48 + lt * 16 + c0];
    float s1v[4][4], s2v[4][4];
#pragma unroll
    for (int sp = 0; sp < 4; ++sp)
#pragma unroll
        for (int rg = 0; rg < 4; ++rg) { s1v[sp][rg] = 0.f; s2v[sp][rg] = 0.f; }
#pragma unroll
    for (int sp = 0; sp < 4; ++sp)
#pragma unroll
        for (int lt = 0; lt < 3; ++lt)
#pragma unroll
            for (int rg = 0; rg < 4; ++rg) {
                float v = acc[sp][lt][rg] + bs[lt];
                acc[sp][lt][rg] = v;
                s1v[sp][rg] += v;
                s2v[sp][rg] += v * v;
            }
#pragma unroll
    for (int off = 1; off < 16; off <<= 1)
#pragma unroll
        for (int sp = 0; sp < 4; ++sp)
#pragma unroll
            for (int rg = 0; rg < 4; ++rg) {
                s1v[sp][rg] += __shfl_xor(s1v[sp][rg], off);
                s2v[sp][rg] += __shfl_xor(s2v[sp][rg], off);
            }
    if (c0 == 0) {
#pragma unroll
        for (int sp = 0; sp < 4; ++sp)
#pragma unroll
            for (int rg = 0; rg < 4; ++rg) {
                int r = sp * 16 + g * 4 + rg;
                pS[w][r] = s1v[sp][rg];
                pS2[w][r] = s2v[sp][rg];
            }
    }
    __syncthreads();
    if (t < 64) {
        float a = pS[0][t] + pS[1][t] + pS[2][t] + pS[3][t];
        float b = pS2[0][t] + pS2[1][t] + pS2[2][t] + pS2[3][t];
        float mean = a * (1.f / 192.f);
        float var = b * (1.f / 192.f) - mean * mean;
        lnM[t] = mean;
        lnR[t] = rsqrtf(var + 1e-5f);
    }
    __syncthreads();

    // m = relu(LN(m_pre)) -> cat
#pragma unroll
    for (int lt = 0; lt < 3; ++lt) {
        int col = w * 48 + lt * 16 + c0;
        float gg = ug[col], bb = ub[col];
#pragma unroll
        for (int sp = 0; sp < 4; ++sp)
#pragma unroll
            for (int rg = 0; rg < 4; ++rg) {
                int r = sp * 16 + g * 4 + rg;
                float v = (acc[sp][lt][rg] - lnM[r]) * lnR[r] * gg + bb;
                cat[r][col] = bf16r(fmaxf(v, 0.f));
            }
    }
    __syncthreads();

    // GEMM2: out = m @ Wu2; wave w -> cols w*16..+15
    f32x4 a2[4];
#pragma unroll
    for (int sp = 0; sp < 4; ++sp) a2[sp] = (f32x4)0.f;
#pragma unroll
    for (int ks = 0; ks < 6; ++ks) {
        const u16* p = pb2 + (size_t)(ks * 4 + w) * 512 + (size_t)lane * 8;
        short8 b = *(const short8*)p;
#pragma unroll
        for (int sp = 0; sp < 4; ++sp) {
            short8 a = *(const short8*)&cat[sp * 16 + c0][ks * 32 + g * 8];
            a2[sp] = __builtin_amdgcn_mfma_f32_16x16x32_bf16(a, b, a2[sp], 0, 0, 0);
        }
    }

    // epilogue: eNew = out + bu2 + eold; write edgeB (+scatter) or f32 edge
    const int col = w * 16 + c0;
    const float bb2 = bu2[col];
#pragma unroll
    for (int sp = 0; sp < 4; ++sp)
#pragma unroll
        for (int rg = 0; rg < 4; ++rg) {
            int r = sp * 16 + g * 4 + rg;
            long ge = eB + r;
            float eNew = a2[sp][rg] + bb2 + eoldf[sp][rg];
            if (SCATTER) {
                edgeB[(size_t)ge * 64 + col] = bf16r(eNew);
                int s2 = src[ge], d2 = dst[ge];
                float msg = fmaxf(node[(size_t)s2 * 64 + col] + eNew, 0.f);
                unsafeAtomicAdd(&agg[(size_t)d2 * 64 + col], msg);
            } else {
                edgeF[(size_t)ge * 64 + col] = eNew;
            }
        }
}

extern "C" void kernel_launch(void* const* d_in, const int* in_sizes, int n_in,
                              void* d_out, int out_size, void* d_ws, size_t ws_size,
                              hipStream_t stream) {
    const int*   x         = (const int*)d_in[0];
    const int*   edge_attr = (const int*)d_in[1];
    const int*   edge_index= (const int*)d_in[2];
    const float* atom_emb  = (const float*)d_in[3];
    const float* bond_emb  = (const float*)d_in[4];
    const float* eps       = (const float*)d_in[5];
    const float* W1        = (const float*)d_in[6];
    const float* b1        = (const float*)d_in[7];
    const float* W2        = (const float*)d_in[8];
    const float* b2        = (const float*)d_in[9];
    const float* ln_g      = (const float*)d_in[10];
    const float* ln_b      = (const float*)d_in[11];
    const float* Wu1       = (const float*)d_in[12];
    const float* bu1       = (const float*)d_in[13];
    const float* ug        = (const float*)d_in[14];
    const float* ub        = (const float*)d_in[15];
    const float* Wu2       = (const float*)d_in[16];
    const float* bu2       = (const float*)d_in[17];

    const int N = GIN_N, E = GIN_E;
    const int* src = edge_index;
    const int* dst = edge_index + E;

    float* node  = (float*)d_out;                    // [N,64]
    float* edgeF = (float*)d_out + (size_t)N * 64;   // [E,64] final f32 only

    // workspace layout (~86 MB)
    char* ws = (char*)d_ws;
    float* agg   = (float*)ws;  ws += (size_t)N * 64 * 4;       // 12.8MB
    u16*   nodeB = (u16*)ws;    ws += (size_t)N * 64 * 2;       // 6.4MB
    u16*   edgeB = (u16*)ws;    ws += (size_t)E * 64 * 2;       // 65.5MB
    u16* pb1     = (u16*)ws;    ws += (size_t)4 * 72 * 512 * 2;
    u16* pb2     = (u16*)ws;    ws += (size_t)4 * 24 * 512 * 2;
    u16* pw1     = (u16*)ws;    ws += (size_t)4 * 16 * 1024 * 2;
    u16* pw2     = (u16*)ws;    ws += (size_t)4 * 16 * 1024 * 2;

    // weight packs
    pack_b1<<<(4 * 72 * 64) / 256, 256, 0, stream>>>(Wu1, pb1, 192, 192, 72);
    pack_b1<<<(4 * 24 * 64) / 256, 256, 0, stream>>>(Wu2, pb2, 192, 64, 24);
    pack_b2<<<(4 * 16 * 64) / 256, 256, 0, stream>>>(W1, pw1, 64, 128, 16);
    pack_b2<<<(4 * 16 * 64) / 256, 256, 0, stream>>>(W2, pw2, 128, 64, 16);

    // encoders + layer-0 aggregation (agg zeroed inside atom_encode)
    atom_encode<<<(N * 64 + 255) / 256, 256, 0, stream>>>(x, atom_emb, node, agg, N);
    bond_encode_scatter<<<(E * 64) / 256, 256, 0, stream>>>(edge_attr, bond_emb,
        edgeB, src, dst, node, agg, E);

    const int nodeBlocks = (N + 63) / 64;
    for (int l = 0; l < 4; ++l) {
        node_mlp<<<nodeBlocks, 256, 0, stream>>>(node, nodeB, agg, eps, l,
            pw1 + (size_t)l * 16 * 1024, pw2 + (size_t)l * 16 * 1024,
            b1 + (size_t)l * 128, b2 + (size_t)l * 64,
            ln_g + (size_t)l * 64, ln_b + (size_t)l * 64, N);
        if (l < 3)
            edge_update_v14<true><<<E / 64, 256, 0, stream>>>(src, dst, node, nodeB,
                edgeB, edgeF, agg,
                pb1 + (size_t)l * 72 * 512, pb2 + (size_t)l * 24 * 512,
                bu1 + (size_t)l * 192,
                ug + (size_t)l * 192, ub + (size_t)l * 192,
                bu2 + (size_t)l * 64);
        else
            edge_update_v14<false><<<E / 64, 256, 0, stream>>>(src, dst, node, nodeB,
                edgeB, edgeF, agg,
                pb1 + (size_t)l * 72 * 512, pb2 + (size_t)l * 24 * 512,
                bu1 + (size_t)l * 192,
                ug + (size_t)l * 192, ub + (size_t)l * 192,
                bu2 + (size_t)l * 64);
    }
}

// Round 18
// 867.082 us; speedup vs baseline: 1.1230x; 1.1230x over previous
//
#include <hip/hip_runtime.h>
#include <hip/hip_bf16.h>

// GINBase: N=50000 nodes, E=512000 edges, D=64, L=4 layers.
// v15 = v13 edge kernel VERBATIM (eold in LDS — reg-array variants spill:
// u16[16] in v10/v12, f32x4[4] in v14, both +88MB WRITE) + v14 node_mlp
// (LDS 51.7KB -> 3 blocks/CU, saved ~50us).

#define GIN_N 50000
#define GIN_E 512000

typedef __attribute__((ext_vector_type(8))) short short8;
typedef __attribute__((ext_vector_type(4))) float f32x4;
typedef unsigned short u16;

__device__ __forceinline__ u16 bf16r(float x) {
    unsigned u = __builtin_bit_cast(unsigned, x);
    u += 0x7fffu + ((u >> 16) & 1u);
    return (u16)(u >> 16);
}
__device__ __forceinline__ float bf16f(u16 h) {
    unsigned u = ((unsigned)h) << 16;
    return __builtin_bit_cast(float, u);
}

// atom encode + agg zeroing fused
__global__ __launch_bounds__(256) void atom_encode(const int* __restrict__ x,
        const float* __restrict__ emb, float* __restrict__ node,
        float* __restrict__ agg, int N) {
    int idx = blockIdx.x * 256 + threadIdx.x;
    int n = idx >> 6, lane = idx & 63;
    if (n >= N) return;
    float s = 0.f;
#pragma unroll
    for (int f = 0; f < 9; ++f) {
        int v = x[n * 9 + f];
        s += emb[(f * 119 + v) * 64 + lane];
    }
    size_t o = (size_t)n * 64 + lane;
    node[o] = s;
    agg[o] = 0.f;
}

// bond encode (bf16 out) + layer-0 message scatter fused (natural order)
__global__ __launch_bounds__(256) void bond_encode_scatter(
        const int* __restrict__ ea, const float* __restrict__ emb,
        u16* __restrict__ edgeB, const int* __restrict__ src,
        const int* __restrict__ dst, const float* __restrict__ node,
        float* __restrict__ agg, int E) {
    int idx = blockIdx.x * 256 + threadIdx.x;
    int e = idx >> 6, lane = idx & 63;
    if (e >= E) return;
    float s = 0.f;
#pragma unroll
    for (int f = 0; f < 3; ++f) {
        int v = ea[e * 3 + f];
        s += emb[(f * 6 + v) * 64 + lane];
    }
    edgeB[(size_t)e * 64 + lane] = bf16r(s);
    int si = src[e], di = dst[e];
    float msg = fmaxf(node[(size_t)si * 64 + lane] + s, 0.f);
    unsafeAtomicAdd(&agg[(size_t)di * 64 + lane], msg);
}

// ---------------- weight pre-pack into MFMA B-fragment order ----------------
__global__ __launch_bounds__(256) void pack_b1(const float* __restrict__ W,
        u16* __restrict__ out, int K, int Nc, int F) {
    int tid = blockIdx.x * 256 + threadIdx.x;
    int lane = tid & 63;
    int frag = (tid >> 6) % F;
    int layer = tid / (F * 64);
    int tpr = Nc / 16;
    int ks = frag / tpr, tt = frag % tpr;
    int k0 = ks * 32 + ((lane >> 4) << 3);
    int col = tt * 16 + (lane & 15);
    const float* w = W + (size_t)layer * K * Nc;
    u16* o = out + ((size_t)layer * F + frag) * 512 + (size_t)lane * 8;
#pragma unroll
    for (int j = 0; j < 8; ++j) o[j] = bf16r(w[(size_t)(k0 + j) * Nc + col]);
}
__global__ __launch_bounds__(256) void pack_b2(const float* __restrict__ W,
        u16* __restrict__ out, int K, int Nc, int F) {
    int tid = blockIdx.x * 256 + threadIdx.x;
    int lane = tid & 63;
    int frag = (tid >> 6) % F;
    int layer = tid / (F * 64);
    int tpr = Nc / 16;
    int ks = frag / tpr, tt = frag % tpr;
    int k0 = ks * 32 + ((lane >> 4) << 3);
    int col = tt * 16 + (lane & 15);
    const float* w = W + (size_t)layer * K * Nc;
    u16* o = out + ((size_t)layer * F + frag) * 1024 + (size_t)lane * 8;
#pragma unroll
    for (int j = 0; j < 8; ++j) {
        float v = w[(size_t)(k0 + j) * Nc + col];
        u16 hi = bf16r(v);
        o[j] = hi;
        o[512 + j] = bf16r(v - bf16f(hi));
    }
}

// ------------- node MLP (in-place): x=(1+eps)*node+agg; MFMA; LN; residual --
__global__ __launch_bounds__(256, 2) void node_mlp(
        float* __restrict__ node, u16* __restrict__ nodeB,
        float* __restrict__ agg,
        const float* __restrict__ epsArr, int l,
        const u16* __restrict__ pw1, const u16* __restrict__ pw2,
        const float* __restrict__ b1, const float* __restrict__ b2,
        const float* __restrict__ lng, const float* __restrict__ lnb, int N) {
    __shared__ u16 xH[64][68], xL[64][68];     // 51.7KB total -> 3 blocks/CU
    __shared__ u16 hH[64][132], hL[64][132];
    __shared__ float pS[4][64], pS2[4][64], lnM[64], lnR[64];
    const int t = threadIdx.x, w = t >> 6, lane = t & 63;
    const int g = lane >> 4, c0 = lane & 15;
    const float epf = 1.f + epsArr[l];

#pragma unroll
    for (int i = 0; i < 16; ++i) {
        int r = w * 16 + i;
        int n = blockIdx.x * 64 + r;
        float x = 0.f;
        if (n < N) {
            size_t o = (size_t)n * 64 + lane;
            x = epf * node[o] + agg[o];
            agg[o] = 0.f;
        }
        u16 h = bf16r(x);
        xH[r][lane] = h;
        xL[r][lane] = bf16r(x - bf16f(h));
    }
    __syncthreads();

    f32x4 a1[4][2];
#pragma unroll
    for (int sp = 0; sp < 4; ++sp)
#pragma unroll
        for (int lt = 0; lt < 2; ++lt) a1[sp][lt] = (f32x4)0.f;
#pragma unroll
    for (int ks = 0; ks < 2; ++ks) {
        short8 aH[4], aL[4];
#pragma unroll
        for (int sp = 0; sp < 4; ++sp) {
            aH[sp] = *(const short8*)&xH[sp * 16 + c0][ks * 32 + g * 8];
            aL[sp] = *(const short8*)&xL[sp * 16 + c0][ks * 32 + g * 8];
        }
#pragma unroll
        for (int lt = 0; lt < 2; ++lt) {
            const u16* p = pw1 + (size_t)(ks * 8 + w * 2 + lt) * 1024 + (size_t)lane * 8;
            short8 bH = *(const short8*)p;
            short8 bL = *(const short8*)(p + 512);
#pragma unroll
            for (int sp = 0; sp < 4; ++sp) {
                a1[sp][lt] = __builtin_amdgcn_mfma_f32_16x16x32_bf16(aH[sp], bH, a1[sp][lt], 0, 0, 0);
                a1[sp][lt] = __builtin_amdgcn_mfma_f32_16x16x32_bf16(aH[sp], bL, a1[sp][lt], 0, 0, 0);
                a1[sp][lt] = __builtin_amdgcn_mfma_f32_16x16x32_bf16(aL[sp], bH, a1[sp][lt], 0, 0, 0);
            }
        }
    }
#pragma unroll
    for (int lt = 0; lt < 2; ++lt) {
        int col = w * 32 + lt * 16 + c0;
        float bias = b1[col];
#pragma unroll
        for (int sp = 0; sp < 4; ++sp)
#pragma unroll
            for (int rg = 0; rg < 4; ++rg) {
                int r = sp * 16 + g * 4 + rg;
                float v = fmaxf(a1[sp][lt][rg] + bias, 0.f);
                u16 h = bf16r(v);
                hH[r][col] = h;
                hL[r][col] = bf16r(v - bf16f(h));
            }
    }
    __syncthreads();

    f32x4 a2[4];
#pragma unroll
    for (int sp = 0; sp < 4; ++sp) a2[sp] = (f32x4)0.f;
#pragma unroll
    for (int ks = 0; ks < 4; ++ks) {
        const u16* p = pw2 + (size_t)(ks * 4 + w) * 1024 + (size_t)lane * 8;
        short8 bH = *(const short8*)p;
        short8 bL = *(const short8*)(p + 512);
#pragma unroll
        for (int sp = 0; sp < 4; ++sp) {
            short8 aH = *(const short8*)&hH[sp * 16 + c0][ks * 32 + g * 8];
            short8 aL = *(const short8*)&hL[sp * 16 + c0][ks * 32 + g * 8];
            a2[sp] = __builtin_amdgcn_mfma_f32_16x16x32_bf16(aH, bH, a2[sp], 0, 0, 0);
            a2[sp] = __builtin_amdgcn_mfma_f32_16x16x32_bf16(aH, bL, a2[sp], 0, 0, 0);
            a2[sp] = __builtin_amdgcn_mfma_f32_16x16x32_bf16(aL, bH, a2[sp], 0, 0, 0);
        }
    }
    float bias2 = b2[w * 16 + c0];
    float s1v[4][4], s2v[4][4];
#pragma unroll
    for (int sp = 0; sp < 4; ++sp)
#pragma unroll
        for (int rg = 0; rg < 4; ++rg) {
            float v = a2[sp][rg] + bias2;
            a2[sp][rg] = v;
            s1v[sp][rg] = v;
            s2v[sp][rg] = v * v;
        }
#pragma unroll
    for (int off = 1; off < 16; off <<= 1)
#pragma unroll
        for (int sp = 0; sp < 4; ++sp)
#pragma unroll
            for (int rg = 0; rg < 4; ++rg) {
                s1v[sp][rg] += __shfl_xor(s1v[sp][rg], off);
                s2v[sp][rg] += __shfl_xor(s2v[sp][rg], off);
            }
    if (c0 == 0) {
#pragma unroll
        for (int sp = 0; sp < 4; ++sp)
#pragma unroll
            for (int rg = 0; rg < 4; ++rg) {
                int r = sp * 16 + g * 4 + rg;
                pS[w][r] = s1v[sp][rg];
                pS2[w][r] = s2v[sp][rg];
            }
    }
    __syncthreads();
    if (t < 64) {
        float a = pS[0][t] + pS[1][t] + pS[2][t] + pS[3][t];
        float b = pS2[0][t] + pS2[1][t] + pS2[2][t] + pS2[3][t];
        float mean = a * (1.f / 64.f);
        float var = b * (1.f / 64.f) - mean * mean;
        lnM[t] = mean;
        lnR[t] = rsqrtf(var + 1e-5f);
    }
    __syncthreads();

    int col = w * 16 + c0;
    float gg = lng[col], bc = lnb[col];
#pragma unroll
    for (int sp = 0; sp < 4; ++sp)
#pragma unroll
        for (int rg = 0; rg < 4; ++rg) {
            int r = sp * 16 + g * 4 + rg;
            int n = blockIdx.x * 64 + r;
            if (n < N) {
                size_t o = (size_t)n * 64 + col;
                float y = (a2[sp][rg] - lnM[r]) * lnR[r] * gg + bc;
                float out = fmaxf(y, 0.f) + node[o];
                node[o] = out;
                nodeB[o] = bf16r(out);
            }
        }
}

// ------------- edge update v15: exact v13 kernel (eold in LDS) --------------
template <bool SCATTER>
__global__ __launch_bounds__(256, 4) void edge_update_v15(
        const int* __restrict__ src, const int* __restrict__ dst,
        const float* __restrict__ node, const u16* __restrict__ nodeB,
        u16* __restrict__ edgeB, float* __restrict__ edgeF,
        float* __restrict__ agg,
        const u16* __restrict__ pb1, const u16* __restrict__ pb2,
        const float* __restrict__ bu1, const float* __restrict__ ug,
        const float* __restrict__ ub, const float* __restrict__ bu2) {
    __shared__ u16 cat[64][200];    // 100 dwords/row: 2-way max on b128 A-frags
    __shared__ u16 eold[64][66];    // edge_old in LDS (reg arrays spill!)
    __shared__ float pS[4][64], pS2[4][64];
    __shared__ float lnM[64], lnR[64];
    const int t = threadIdx.x, w = t >> 6, lane = t & 63;
    const int g = lane >> 4, c0 = lane & 15;
    const long eB = (long)blockIdx.x * 64;   // natural order

    // stage: pure u16 copies
#pragma unroll
    for (int i = 0; i < 16; ++i) {
        int r = w * 16 + i;
        long ge = eB + r;
        int s = src[ge], d = dst[ge];
        cat[r][lane]       = nodeB[(size_t)s * 64 + lane];
        cat[r][64 + lane]  = nodeB[(size_t)d * 64 + lane];
        u16 ev = edgeB[(size_t)ge * 64 + lane];
        cat[r][128 + lane] = ev;
        eold[r][lane] = ev;
    }
    __syncthreads();

    // GEMM1: m_pre = cat @ Wu1; wave w -> cols w*48..+47 (sp-reuse x4)
    f32x4 acc[4][3];
#pragma unroll
    for (int sp = 0; sp < 4; ++sp)
#pragma unroll
        for (int lt = 0; lt < 3; ++lt) acc[sp][lt] = (f32x4)0.f;
#pragma unroll
    for (int ks = 0; ks < 6; ++ks) {
        short8 a[4];
#pragma unroll
        for (int sp = 0; sp < 4; ++sp)
            a[sp] = *(const short8*)&cat[sp * 16 + c0][ks * 32 + g * 8];
#pragma unroll
        for (int lt = 0; lt < 3; ++lt) {
            const u16* p = pb1 + (size_t)(ks * 12 + w * 3 + lt) * 512 + (size_t)lane * 8;
            short8 b = *(const short8*)p;
#pragma unroll
            for (int sp = 0; sp < 4; ++sp)
                acc[sp][lt] = __builtin_amdgcn_mfma_f32_16x16x32_bf16(a[sp], b, acc[sp][lt], 0, 0, 0);
        }
    }

    float bs[3];
#pragma unroll
    for (int lt = 0; lt < 3; ++lt) bs[lt] = bu1[w * 48 + lt * 16 + c0];
    float s1v[4][4], s2v[4][4];
#pragma unroll
    for (int sp = 0; sp < 4; ++sp)
#pragma unroll
        for (int rg = 0; rg < 4; ++rg) { s1v[sp][rg] = 0.f; s2v[sp][rg] = 0.f; }
#pragma unroll
    for (int sp = 0; sp < 4; ++sp)
#pragma unroll
        for (int lt = 0; lt < 3; ++lt)
#pragma unroll
            for (int rg = 0; rg < 4; ++rg) {
                float v = acc[sp][lt][rg] + bs[lt];
                acc[sp][lt][rg] = v;
                s1v[sp][rg] += v;
                s2v[sp][rg] += v * v;
            }
#pragma unroll
    for (int off = 1; off < 16; off <<= 1)
#pragma unroll
        for (int sp = 0; sp < 4; ++sp)
#pragma unroll
            for (int rg = 0; rg < 4; ++rg) {
                s1v[sp][rg] += __shfl_xor(s1v[sp][rg], off);
                s2v[sp][rg] += __shfl_xor(s2v[sp][rg], off);
            }
    if (c0 == 0) {
#pragma unroll
        for (int sp = 0; sp < 4; ++sp)
#pragma unroll
            for (int rg = 0; rg < 4; ++rg) {
                int r = sp * 16 + g * 4 + rg;
                pS[w][r] = s1v[sp][rg];
                pS2[w][r] = s2v[sp][rg];
            }
    }
    __syncthreads();
    if (t < 64) {
        float a = pS[0][t] + pS[1][t] + pS[2][t] + pS[3][t];
        float b = pS2[0][t] + pS2[1][t] + pS2[2][t] + pS2[3][t];
        float mean = a * (1.f / 192.f);
        float var = b * (1.f / 192.f) - mean * mean;
        lnM[t] = mean;
        lnR[t] = rsqrtf(var + 1e-5f);
    }
    __syncthreads();

    // m = relu(LN(m_pre)) -> cat
#pragma unroll
    for (int lt = 0; lt < 3; ++lt) {
        int col = w * 48 + lt * 16 + c0;
        float gg = ug[col], bb = ub[col];
#pragma unroll
        for (int sp = 0; sp < 4; ++sp)
#pragma unroll
            for (int rg = 0; rg < 4; ++rg) {
                int r = sp * 16 + g * 4 + rg;
                float v = (acc[sp][lt][rg] - lnM[r]) * lnR[r] * gg + bb;
                cat[r][col] = bf16r(fmaxf(v, 0.f));
            }
    }
    __syncthreads();

    // GEMM2: out = m @ Wu2; wave w -> cols w*16..+15
    f32x4 a2[4];
#pragma unroll
    for (int sp = 0; sp < 4; ++sp) a2[sp] = (f32x4)0.f;
#pragma unroll
    for (int ks = 0; ks < 6; ++ks) {
        const u16* p = pb2 + (size_t)(ks * 4 + w) * 512 + (size_t)lane * 8;
        short8 b = *(const short8*)p;
#pragma unroll
        for (int sp = 0; sp < 4; ++sp) {
            short8 a = *(const short8*)&cat[sp * 16 + c0][ks * 32 + g * 8];
            a2[sp] = __builtin_amdgcn_mfma_f32_16x16x32_bf16(a, b, a2[sp], 0, 0, 0);
        }
    }

    // epilogue: eNew = out + bu2 + eold; write edgeB (+scatter) or f32 edge
    const int col = w * 16 + c0;
    const float bb2 = bu2[col];
#pragma unroll
    for (int sp = 0; sp < 4; ++sp)
#pragma unroll
        for (int rg = 0; rg < 4; ++rg) {
            int r = sp * 16 + g * 4 + rg;
            long ge = eB + r;
            float eNew = a2[sp][rg] + bb2 + bf16f(eold[r][col]);
            if (SCATTER) {
                edgeB[(size_t)ge * 64 + col] = bf16r(eNew);
                int s2 = src[ge], d2 = dst[ge];
                float msg = fmaxf(node[(size_t)s2 * 64 + col] + eNew, 0.f);
                unsafeAtomicAdd(&agg[(size_t)d2 * 64 + col], msg);
            } else {
                edgeF[(size_t)ge * 64 + col] = eNew;
            }
        }
}

extern "C" void kernel_launch(void* const* d_in, const int* in_sizes, int n_in,
                              void* d_out, int out_size, void* d_ws, size_t ws_size,
                              hipStream_t stream) {
    const int*   x         = (const int*)d_in[0];
    const int*   edge_attr = (const int*)d_in[1];
    const int*   edge_index= (const int*)d_in[2];
    const float* atom_emb  = (const float*)d_in[3];
    const float* bond_emb  = (const float*)d_in[4];
    const float* eps       = (const float*)d_in[5];
    const float* W1        = (const float*)d_in[6];
    const float* b1        = (const float*)d_in[7];
    const float* W2        = (const float*)d_in[8];
    const float* b2        = (const float*)d_in[9];
    const float* ln_g      = (const float*)d_in[10];
    const float* ln_b      = (const float*)d_in[11];
    const float* Wu1       = (const float*)d_in[12];
    const float* bu1       = (const float*)d_in[13];
    const float* ug        = (const float*)d_in[14];
    const float* ub        = (const float*)d_in[15];
    const float* Wu2       = (const float*)d_in[16];
    const float* bu2       = (const float*)d_in[17];

    const int N = GIN_N, E = GIN_E;
    const int* src = edge_index;
    const int* dst = edge_index + E;

    float* node  = (float*)d_out;                    // [N,64]
    float* edgeF = (float*)d_out + (size_t)N * 64;   // [E,64] final f32 only

    // workspace layout (~86 MB)
    char* ws = (char*)d_ws;
    float* agg   = (float*)ws;  ws += (size_t)N * 64 * 4;       // 12.8MB
    u16*   nodeB = (u16*)ws;    ws += (size_t)N * 64 * 2;       // 6.4MB
    u16*   edgeB = (u16*)ws;    ws += (size_t)E * 64 * 2;       // 65.5MB
    u16* pb1     = (u16*)ws;    ws += (size_t)4 * 72 * 512 * 2;
    u16* pb2     = (u16*)ws;    ws += (size_t)4 * 24 * 512 * 2;
    u16* pw1     = (u16*)ws;    ws += (size_t)4 * 16 * 1024 * 2;
    u16* pw2     = (u16*)ws;    ws += (size_t)4 * 16 * 1024 * 2;

    // weight packs
    pack_b1<<<(4 * 72 * 64) / 256, 256, 0, stream>>>(Wu1, pb1, 192, 192, 72);
    pack_b1<<<(4 * 24 * 64) / 256, 256, 0, stream>>>(Wu2, pb2, 192, 64, 24);
    pack_b2<<<(4 * 16 * 64) / 256, 256, 0, stream>>>(W1, pw1, 64, 128, 16);
    pack_b2<<<(4 * 16 * 64) / 256, 256, 0, stream>>>(W2, pw2, 128, 64, 16);

    // encoders + layer-0 aggregation (agg zeroed inside atom_encode)
    atom_encode<<<(N * 64 + 255) / 256, 256, 0, stream>>>(x, atom_emb, node, agg, N);
    bond_encode_scatter<<<(E * 64) / 256, 256, 0, stream>>>(edge_attr, bond_emb,
        edgeB, src, dst, node, agg, E);

    const int nodeBlocks = (N + 63) / 64;
    for (int l = 0; l < 4; ++l) {
        node_mlp<<<nodeBlocks, 256, 0, stream>>>(node, nodeB, agg, eps, l,
            pw1 + (size_t)l * 16 * 1024, pw2 + (size_t)l * 16 * 1024,
            b1 + (size_t)l * 128, b2 + (size_t)l * 64,
            ln_g + (size_t)l * 64, ln_b + (size_t)l * 64, N);
        if (l < 3)
            edge_update_v15<true><<<E / 64, 256, 0, stream>>>(src, dst, node, nodeB,
                edgeB, edgeF, agg,
                pb1 + (size_t)l * 72 * 512, pb2 + (size_t)l * 24 * 512,
                bu1 + (size_t)l * 192,
                ug + (size_t)l * 192, ub + (size_t)l * 192,
                bu2 + (size_t)l * 64);
        else
            edge_update_v15<false><<<E / 64, 256, 0, stream>>>(src, dst, node, nodeB,
                edgeB, edgeF, agg,
                pb1 + (size_t)l * 72 * 512, pb2 + (size_t)l * 24 * 512,
                bu1 + (size_t)l * 192,
                ug + (size_t)l * 192, ub + (size_t)l * 192,
                bu2 + (size_t)l * 64);
    }
}